// Round 1
// baseline (430.991 us; speedup 1.0000x reference)
//
#include <hip/hip_runtime.h>

typedef unsigned short u16;
typedef float f32x4 __attribute__((ext_vector_type(4)));
typedef short s16x8 __attribute__((ext_vector_type(8)));
typedef short s16x4 __attribute__((ext_vector_type(4)));

__device__ __forceinline__ u16 f2b(float f) {
  union { float f; unsigned u; } v; v.f = f;
  unsigned r = v.u + 0x7fffu + ((v.u >> 16) & 1u);
  return (u16)(r >> 16);
}
__device__ __forceinline__ float b2f(u16 b) {
  union { unsigned u; float f; } v; v.u = ((unsigned)b) << 16;
  return v.f;
}
__device__ __forceinline__ f32x4 mfma_bf16(s16x8 a, s16x8 b, f32x4 c) {
  return __builtin_amdgcn_mfma_f32_16x16x32_bf16(a, b, c, 0, 0, 0);
}
__device__ __forceinline__ void gl_lds16(const u16* g, u16* l) {
  __builtin_amdgcn_global_load_lds(
      (const __attribute__((address_space(1))) void*)g,
      (__attribute__((address_space(3))) void*)l, 16, 0, 0);
}
// XOR-swizzled LDS index helpers (u16 units). byte ^= (row&7)<<4.
// kswz: stride-128-u16 tiles (Ks [64][128]); vswz: stride-64-u16 (Vs/Ps [128][64]).
__device__ __forceinline__ int kswz(int r, int c) { return ((r << 7) + c) ^ ((r & 7) << 3); }
__device__ __forceinline__ int vswz(int r, int c) { return ((r << 6) + c) ^ ((r & 7) << 3); }

// ---------------------------------------------------------------------------
// x fp32 -> bf16
// ---------------------------------------------------------------------------
__global__ void conv_x(const float* __restrict__ in, u16* __restrict__ out, int n) {
  int i = (blockIdx.x * 256 + threadIdx.x) * 8;
  if (i >= n) return;
  f32x4 a = *(const f32x4*)(in + i);
  f32x4 b = *(const f32x4*)(in + i + 4);
  s16x8 o = {(short)f2b(a.x), (short)f2b(a.y), (short)f2b(a.z), (short)f2b(a.w),
             (short)f2b(b.x), (short)f2b(b.y), (short)f2b(b.z), (short)f2b(b.w)};
  *(s16x8*)(out + i) = o;
}

// ---------------------------------------------------------------------------
// Weight transpose+convert fp32->bf16, 64x64 tiles.
// ---------------------------------------------------------------------------
__global__ void transW_qkv(const float* __restrict__ Wq, const float* __restrict__ Wk,
                           const float* __restrict__ Wv, u16* __restrict__ WqkvT) {
  __shared__ u16 tile[64][68];
  const int ox = blockIdx.x * 64;   // output-row base == source-col base
  const int oy = blockIdx.y * 64;   // source-row base
  const float* src; int scol, C;
  if (ox < 2048)      { src = Wq; scol = ox;        C = 2048; }
  else if (ox < 2560) { src = Wk; scol = ox - 2048; C = 512;  }
  else                { src = Wv; scol = ox - 2560; C = 512;  }
  const int t = threadIdx.x, lr = t >> 4, c4 = (t & 15) * 4;
#pragma unroll
  for (int p = 0; p < 4; ++p) {
    int r = p * 16 + lr;
    f32x4 v = *(const f32x4*)(src + (size_t)(oy + r) * C + scol + c4);
    s16x4 pk = {(short)f2b(v.x), (short)f2b(v.y), (short)f2b(v.z), (short)f2b(v.w)};
    *(s16x4*)(&tile[r][c4]) = pk;
  }
  __syncthreads();
#pragma unroll
  for (int q = 0; q < 4; ++q) {
    int oc = q * 16 + lr;
    s16x4 pk = {(short)tile[c4 + 0][oc], (short)tile[c4 + 1][oc],
                (short)tile[c4 + 2][oc], (short)tile[c4 + 3][oc]};
    *(s16x4*)(WqkvT + (size_t)(ox + oc) * 2048 + oy + c4) = pk;
  }
}

__global__ void transW_o(const float* __restrict__ Wo, u16* __restrict__ WoT) {
  __shared__ u16 tile[64][68];
  const int ox = blockIdx.x * 64, oy = blockIdx.y * 64;
  const int t = threadIdx.x, lr = t >> 4, c4 = (t & 15) * 4;
#pragma unroll
  for (int p = 0; p < 4; ++p) {
    int r = p * 16 + lr;
    f32x4 v = *(const f32x4*)(Wo + (size_t)(oy + r) * 2048 + ox + c4);
    s16x4 pk = {(short)f2b(v.x), (short)f2b(v.y), (short)f2b(v.z), (short)f2b(v.w)};
    *(s16x4*)(&tile[r][c4]) = pk;
  }
  __syncthreads();
#pragma unroll
  for (int q = 0; q < 4; ++q) {
    int oc = q * 16 + lr;
    s16x4 pk = {(short)tile[c4 + 0][oc], (short)tile[c4 + 1][oc],
                (short)tile[c4 + 2][oc], (short)tile[c4 + 3][oc]};
    *(s16x4*)(WoT + (size_t)(ox + oc) * 2048 + oy + c4) = pk;
  }
}

// v slice of qkv (cols 2560..3071) -> vT[512][2048]
__global__ void transpose_v(const u16* __restrict__ qkv, u16* __restrict__ vT) {
  __shared__ u16 tile[64][68];
  const int bx = blockIdx.x * 64, by = blockIdx.y * 64;
  const int t = threadIdx.x, lr = t >> 4, c4 = (t & 15) * 4;
#pragma unroll
  for (int p = 0; p < 4; ++p) {
    int r = p * 16 + lr;
    s16x4 v = *(const s16x4*)(qkv + (size_t)(by + r) * 3072 + 2560 + bx + c4);
    *(s16x4*)(&tile[r][c4]) = v;
  }
  __syncthreads();
#pragma unroll
  for (int q = 0; q < 4; ++q) {
    int oc = q * 16 + lr;
    s16x4 pk = {(short)tile[c4 + 0][oc], (short)tile[c4 + 1][oc],
                (short)tile[c4 + 2][oc], (short)tile[c4 + 3][oc]};
    *(s16x4*)(vT + (size_t)(bx + oc) * 2048 + by + c4) = pk;
  }
}

// ---------------------------------------------------------------------------
// 128x128 GEMM core (m97 structure), K-range parametrized for split-K.
// ---------------------------------------------------------------------------
__device__ __forceinline__ void gemm_core(const u16* __restrict__ A,
                                          const u16* __restrict__ Bt,
                                          int kbeg, int kend, int K,
                                          int m0, int n0,
                                          f32x4 (*acc)[4], u16* As, u16* Bs) {
  const int t = threadIdx.x;
  const int wave = t >> 6, lane = t & 63, quad = lane >> 4, lc = lane & 15;
  const int wm = (wave >> 1) * 64, wn = (wave & 1) * 64;
  for (int k0 = kbeg; k0 < kend; k0 += 32) {
#pragma unroll
    for (int h = 0; h < 2; ++h) {
      int ch = h * 256 + t, row = ch >> 2, kc = (ch & 3) * 8;
      gl_lds16(A  + (size_t)(m0 + row) * K + k0 + kc, As + (size_t)(h * 256 + wave * 64) * 8);
      gl_lds16(Bt + (size_t)(n0 + row) * K + k0 + kc, Bs + (size_t)(h * 256 + wave * 64) * 8);
    }
    __syncthreads();
    s16x8 af[4], bfr[4];
#pragma unroll
    for (int i = 0; i < 4; ++i)
      af[i] = *(const s16x8*)(As + (wm + i * 16 + lc) * 32 + quad * 8);
#pragma unroll
    for (int j = 0; j < 4; ++j)
      bfr[j] = *(const s16x8*)(Bs + (wn + j * 16 + lc) * 32 + quad * 8);
#pragma unroll
    for (int i = 0; i < 4; ++i)
#pragma unroll
      for (int j = 0; j < 4; ++j)
        acc[i][j] = mfma_bf16(af[i], bfr[j], acc[i][j]);
    __syncthreads();
  }
}

// QKV GEMM half: P[kh] = x @ WqkvT^T over K half.  grid (24,16,2).
__global__ __launch_bounds__(256, 2) void gemm_qkv_half(const u16* __restrict__ A,
                                                        const u16* __restrict__ Bt,
                                                        u16* __restrict__ P) {
  __shared__ __align__(16) u16 As[128 * 32];
  __shared__ __align__(16) u16 Bs[128 * 32];
  const int kh = blockIdx.z;
  const int n0 = blockIdx.x * 128, m0 = blockIdx.y * 128;
  const int lane = threadIdx.x & 63, wave = threadIdx.x >> 6;
  const int quad = lane >> 4, lc = lane & 15;
  const int wm = (wave >> 1) * 64, wn = (wave & 1) * 64;
  const f32x4 z = {0.f, 0.f, 0.f, 0.f};
  f32x4 acc[4][4];
#pragma unroll
  for (int i = 0; i < 4; ++i)
#pragma unroll
    for (int j = 0; j < 4; ++j) acc[i][j] = z;
  gemm_core(A, Bt, kh * 1024, kh * 1024 + 1024, 2048, m0, n0, acc, As, Bs);
  u16* Pk = P + (size_t)kh * (2048 * 3072);
#pragma unroll
  for (int i = 0; i < 4; ++i)
#pragma unroll
    for (int j = 0; j < 4; ++j)
#pragma unroll
      for (int r = 0; r < 4; ++r)
        Pk[(size_t)(m0 + wm + i * 16 + quad * 4 + r) * 3072 + n0 + wn + j * 16 + lc] =
            f2b(acc[i][j][r]);
}

// Reduce halves + RoPE (pairs are intra-vector) -> qkv bf16.  grid 3072.
__global__ void reduce_rope(const u16* __restrict__ P, u16* __restrict__ qkv) {
  const int lin = blockIdx.x * 256 + threadIdx.x;   // 0..786431
  const int row = lin / 384, c8 = (lin - row * 384) * 8;
  const u16* p0 = P + (size_t)row * 3072 + c8;
  s16x8 a = *(const s16x8*)p0;
  s16x8 b = *(const s16x8*)(p0 + 6291456);          // + 2048*3072
  float v[8];
#pragma unroll
  for (int i = 0; i < 8; ++i) v[i] = b2f((u16)a[i]) + b2f((u16)b[i]);
  if (c8 < 2560) {                                   // q|k cols get RoPE
#pragma unroll
    for (int h = 0; h < 4; ++h) {
      const int i = 2 * h;
      const int ip = ((c8 + i) & 127) >> 1;          // pair idx within head
      const float ang = (float)row * exp2f(-0.20762050593046014f * (float)ip);
      float sv, cv;
      sincosf(ang, &sv, &cv);
      const float e = v[i], o = v[i + 1];
      v[i]     = e * cv - o * sv;
      v[i + 1] = e * sv + o * cv;
    }
  }
  s16x8 o;
#pragma unroll
  for (int i = 0; i < 8; ++i) o[i] = (short)f2b(v[i]);
  *(s16x8*)(qkv + (size_t)row * 3072 + c8) = o;
}

// Out GEMM half: Po[kh] = ctx @ WoT^T over K half.  grid (16,16,2).
__global__ __launch_bounds__(256, 2) void gemm_out_half(const u16* __restrict__ A,
                                                        const u16* __restrict__ Bt,
                                                        u16* __restrict__ Po) {
  __shared__ __align__(16) u16 As[128 * 32];
  __shared__ __align__(16) u16 Bs[128 * 32];
  const int kh = blockIdx.z;
  const int n0 = blockIdx.x * 128, m0 = blockIdx.y * 128;
  const int lane = threadIdx.x & 63, wave = threadIdx.x >> 6;
  const int quad = lane >> 4, lc = lane & 15;
  const int wm = (wave >> 1) * 64, wn = (wave & 1) * 64;
  const f32x4 z = {0.f, 0.f, 0.f, 0.f};
  f32x4 acc[4][4];
#pragma unroll
  for (int i = 0; i < 4; ++i)
#pragma unroll
    for (int j = 0; j < 4; ++j) acc[i][j] = z;
  gemm_core(A, Bt, kh * 1024, kh * 1024 + 1024, 2048, m0, n0, acc, As, Bs);
  u16* Pk = Po + (size_t)kh * (2048 * 2048);
#pragma unroll
  for (int i = 0; i < 4; ++i)
#pragma unroll
    for (int j = 0; j < 4; ++j)
#pragma unroll
      for (int r = 0; r < 4; ++r)
        Pk[(size_t)(m0 + wm + i * 16 + quad * 4 + r) * 2048 + n0 + wn + j * 16 + lc] =
            f2b(acc[i][j][r]);
}

// Reduce out halves -> fp32 d_out.  grid 2048.
__global__ void reduce_out(const u16* __restrict__ Po, float* __restrict__ out) {
  const int lin = blockIdx.x * 256 + threadIdx.x;   // 0..524287
  const u16* p0 = Po + (size_t)lin * 8;
  s16x8 a = *(const s16x8*)p0;
  s16x8 b = *(const s16x8*)(p0 + 4194304);          // + 2048*2048
  f32x4 o0, o1;
#pragma unroll
  for (int i = 0; i < 4; ++i) o0[i] = b2f((u16)a[i]) + b2f((u16)b[i]);
#pragma unroll
  for (int i = 0; i < 4; ++i) o1[i] = b2f((u16)a[i + 4]) + b2f((u16)b[i + 4]);
  *(f32x4*)(out + (size_t)lin * 8) = o0;
  *(f32x4*)(out + (size_t)lin * 8 + 4) = o1;
}

// ---------------------------------------------------------------------------
// Attention v5: XOR-swizzled unpadded LDS (48 KiB -> 3 blocks/CU),
// unmasked-tile fast path, setprio around MFMA clusters, longest-chunks-first
// block ordering (idx reversed; attn_combine matches).
// ---------------------------------------------------------------------------
__global__ __launch_bounds__(256, 3) void attn_k(const u16* __restrict__ qkv,
                                                 const u16* __restrict__ vT,
                                                 u16* __restrict__ Opart,
                                                 float* __restrict__ Lpart) {
  const int bid = blockIdx.x;
  const int hq = bid / 40, idx = 39 - (bid % 40);   // reversed: big chunks first
  int qt, c;
  if (idx < 4)       { qt = idx;                          c = 0; }
  else if (idx < 12) { int w = idx - 4;  qt = 4 + (w >> 1);  c = w & 1; }
  else if (idx < 24) { int w = idx - 12; qt = 8 + w / 3;     c = w % 3; }
  else               { int w = idx - 24; qt = 12 + (w >> 2); c = w & 3; }
  const int s0 = c * 8;
  const int s1 = min(c * 8 + 8, 2 * qt + 2);

  const int kvh = hq & 3;
  const int qc0 = hq << 7, kc0 = 2048 + (kvh << 7), vr0 = kvh << 7;

  // Unpadded, XOR-swizzled tiles: 3 x 16384 B = 48 KiB -> 3 blocks/CU.
  __shared__ __align__(16) u16 Ks[64 * 128];   // [j][d], kswz
  __shared__ __align__(16) u16 Vs[128 * 64];   // [d][j], vswz
  __shared__ __align__(16) u16 Ps[128 * 64];   // [q][j], vswz (per-wave private rows)

  const int t = threadIdx.x, wave = t >> 6, lane = t & 63;
  const int quad = lane >> 4, lc = lane & 15;
  const int kr = t >> 4, kc = (t & 15) * 8;
  const int vr = t >> 3, vc = (t & 7) * 8;

  s16x8 qf[2][4];
#pragma unroll
  for (int i = 0; i < 2; ++i)
#pragma unroll
    for (int ks = 0; ks < 4; ++ks)
      qf[i][ks] = *(const s16x8*)(qkv +
          (size_t)(qt * 128 + wave * 32 + i * 16 + lc) * 3072 +
          qc0 + ks * 32 + quad * 8);

  const f32x4 z = {0.f, 0.f, 0.f, 0.f};
  f32x4 oa[2][8];
#pragma unroll
  for (int i = 0; i < 2; ++i)
#pragma unroll
    for (int n = 0; n < 8; ++n) oa[i][n] = z;
  float Ls[2][4] = {{0.f, 0.f, 0.f, 0.f}, {0.f, 0.f, 0.f, 0.f}};
  const float scale2 = 0.12751744545f;

  s16x8 kpf[4], vpf[4];
  {
    const int j0 = s0 * 64;
#pragma unroll
    for (int p = 0; p < 4; ++p)
      kpf[p] = *(const s16x8*)(qkv + (size_t)(j0 + p * 16 + kr) * 3072 + kc0 + kc);
#pragma unroll
    for (int p = 0; p < 4; ++p)
      vpf[p] = *(const s16x8*)(vT + (size_t)(vr0 + p * 32 + vr) * 2048 + j0 + vc);
  }

  for (int tile = s0; tile < s1; ++tile) {
    const int j0 = tile * 64;
    __syncthreads();
#pragma unroll
    for (int p = 0; p < 4; ++p)
      *(s16x8*)(Ks + kswz(p * 16 + kr, kc)) = kpf[p];
#pragma unroll
    for (int p = 0; p < 4; ++p)
      *(s16x8*)(Vs + vswz(p * 32 + vr, vc)) = vpf[p];
    __syncthreads();
    if (tile + 1 < s1) {
      const int j1 = j0 + 64;
#pragma unroll
      for (int p = 0; p < 4; ++p)
        kpf[p] = *(const s16x8*)(qkv + (size_t)(j1 + p * 16 + kr) * 3072 + kc0 + kc);
#pragma unroll
      for (int p = 0; p < 4; ++p)
        vpf[p] = *(const s16x8*)(vT + (size_t)(vr0 + p * 32 + vr) * 2048 + j1 + vc);
    }
    f32x4 sa[2][4];
#pragma unroll
    for (int i = 0; i < 2; ++i)
#pragma unroll
      for (int n = 0; n < 4; ++n) sa[i][n] = z;
    __builtin_amdgcn_s_setprio(1);
#pragma unroll
    for (int ks = 0; ks < 4; ++ks)
#pragma unroll
      for (int n = 0; n < 4; ++n) {
        s16x8 bf = *(const s16x8*)(Ks + kswz(n * 16 + lc, ks * 32 + quad * 8));
        sa[0][n] = mfma_bf16(qf[0][ks], bf, sa[0][n]);
        sa[1][n] = mfma_bf16(qf[1][ks], bf, sa[1][n]);
      }
    __builtin_amdgcn_s_setprio(0);
    if (j0 + 64 <= qt * 128) {
      // Fully-unmasked tile (block-uniform): no causal compare needed.
#pragma unroll
      for (int i = 0; i < 2; ++i)
#pragma unroll
        for (int n = 0; n < 4; ++n)
#pragma unroll
          for (int r = 0; r < 4; ++r) {
            float e = exp2f(sa[i][n][r] * scale2);
            Ps[vswz(wave * 32 + i * 16 + quad * 4 + r, n * 16 + lc)] = f2b(e);
            Ls[i][r] += e;
          }
    } else {
#pragma unroll
      for (int i = 0; i < 2; ++i) {
        const int qrow_base = qt * 128 + wave * 32 + i * 16 + quad * 4;
#pragma unroll
        for (int n = 0; n < 4; ++n) {
          int jc = j0 + n * 16 + lc;
#pragma unroll
          for (int r = 0; r < 4; ++r) {
            float e = (jc <= qrow_base + r) ? exp2f(sa[i][n][r] * scale2) : 0.f;
            Ps[vswz(wave * 32 + i * 16 + quad * 4 + r, n * 16 + lc)] = f2b(e);
            Ls[i][r] += e;
          }
        }
      }
    }
    __builtin_amdgcn_s_setprio(1);
#pragma unroll
    for (int ks = 0; ks < 2; ++ks)
#pragma unroll
      for (int i = 0; i < 2; ++i) {
        s16x8 af = *(const s16x8*)(Ps + vswz(wave * 32 + i * 16 + lc,
                                             ks * 32 + quad * 8));
#pragma unroll
        for (int n = 0; n < 8; ++n) {
          s16x8 bf = *(const s16x8*)(Vs + vswz(n * 16 + lc, ks * 32 + quad * 8));
          oa[i][n] = mfma_bf16(af, bf, oa[i][n]);
        }
      }
    __builtin_amdgcn_s_setprio(0);
  }
#pragma unroll
  for (int i = 0; i < 2; ++i)
#pragma unroll
    for (int r = 0; r < 4; ++r) {
      float s = Ls[i][r];
      s += __shfl_xor(s, 1);
      s += __shfl_xor(s, 2);
      s += __shfl_xor(s, 4);
      s += __shfl_xor(s, 8);
      Ls[i][r] = s;
    }
  u16* Ob = Opart + (size_t)bid * (128 * 128);
  if (lc == 0) {
#pragma unroll
    for (int i = 0; i < 2; ++i)
#pragma unroll
      for (int r = 0; r < 4; ++r)
        Lpart[(size_t)bid * 128 + wave * 32 + i * 16 + quad * 4 + r] = Ls[i][r];
  }
#pragma unroll
  for (int i = 0; i < 2; ++i)
#pragma unroll
    for (int n = 0; n < 8; ++n)
#pragma unroll
      for (int r = 0; r < 4; ++r)
        Ob[(wave * 32 + i * 16 + quad * 4 + r) * 128 + n * 16 + lc] =
            f2b(oa[i][n][r]);
}

__global__ void attn_combine(const u16* __restrict__ Opart,
                             const float* __restrict__ Lpart,
                             u16* __restrict__ ctx) {
  const int hq = blockIdx.y, kvh = hq & 3, sg = hq >> 2;
  const int lin = blockIdx.x * 256 + threadIdx.x;
  const int token = lin >> 4, d8 = (lin & 15) << 3;
  const int qt = token >> 7, row = token & 127;
  const int tier = qt >> 2;
  const int btab[4] = {0, 4, 12, 24};
  const int base = btab[tier] + (qt & 3) * (tier + 1);
  const int cnt = tier + 1;
  float acc[8] = {0.f, 0.f, 0.f, 0.f, 0.f, 0.f, 0.f, 0.f};
  float L = 0.f;
  for (int c = 0; c < cnt; ++c) {
    const int b = hq * 40 + (39 - (base + c));   // matches reversed attn_k mapping
    L += Lpart[(size_t)b * 128 + row];
    s16x8 o = *(const s16x8*)(Opart + (size_t)b * 16384 + row * 128 + d8);
#pragma unroll
    for (int i = 0; i < 8; ++i) acc[i] += b2f((u16)o[i]);
  }
  const float inv = 1.f / L;
  s16x8 out;
#pragma unroll
  for (int i = 0; i < 8; ++i) out[i] = (short)f2b(acc[i] * inv);
  *(s16x8*)(ctx + (size_t)token * 2048 + ((kvh * 4 + sg) << 7) + d8) = out;
}

// ---------------------------------------------------------------------------
extern "C" void kernel_launch(void* const* d_in, const int* in_sizes, int n_in,
                              void* d_out, int out_size, void* d_ws, size_t ws_size,
                              hipStream_t stream) {
  const float* x  = (const float*)d_in[0];
  const float* Wq = (const float*)d_in[1];
  const float* Wk = (const float*)d_in[2];
  const float* Wv = (const float*)d_in[3];
  const float* Wo = (const float*)d_in[4];

  // Workspace choreography (peak ~50.3 MB; 52.4 MB proven available in R3):
  //  [0 .. 8.39M)    xb          -> later qkvb (12.58M) -> later WoT (8.39M)
  //  [8.39 .. 20.97) WqkvT       -> later vTb@12.58 (2.1M) + Lpart@14.68 (.33M)
  //  [20.97 .. 46.14) Pq0|Pq1    -> later Opart (20.97M) -> later Po0|Po1 (16.8M)
  //  [41.94 .. 50.33) ctxb (8.39M, starts exactly at Opart end)
  char* base = (char*)d_ws;
  u16*   xb    = (u16*)(base);
  u16*   qkvb  = (u16*)(base);                       // aliases xb+WqkvT head
  u16*   WoT   = (u16*)(base);                       // aliases qkvb (dead)
  u16*   WqkvT = (u16*)(base + 8388608);
  u16*   vTb   = (u16*)(base + 12582912);            // aliases WqkvT (dead)
  float* Lpart = (float*)(base + 14680064);
  u16*   Pq    = (u16*)(base + 20971520);            // 2 x 12.58M
  u16*   Opart = (u16*)(base + 20971520);            // aliases Pq (dead)
  u16*   Po    = (u16*)(base + 20971520);            // aliases Opart (dead)
  u16*   ctxb  = (u16*)(base + 41943040);

  // 1) convert x; transpose qkv weights
  conv_x<<<2048, 256, 0, stream>>>(x, xb, 2048 * 2048);
  transW_qkv<<<dim3(48, 32), 256, 0, stream>>>(Wq, Wk, Wv, WqkvT);

  // 2) split-K QKV projection -> bf16 partials -> reduce + RoPE
  gemm_qkv_half<<<dim3(24, 16, 2), 256, 0, stream>>>(xb, WqkvT, Pq);
  reduce_rope<<<3072, 256, 0, stream>>>(Pq, qkvb);

  // 3) v -> vT
  transpose_v<<<dim3(8, 32), 256, 0, stream>>>(qkvb, vTb);

  // 4) chunked attention + combine   [Opart overwrites Pq]
  attn_k<<<640, 256, 0, stream>>>(qkvb, vTb, Opart, Lpart);
  attn_combine<<<dim3(128, 16), 256, 0, stream>>>(Opart, Lpart, ctxb);

  // 5) transpose Wo (qkvb dead now), split-K out projection, reduce -> fp32
  transW_o<<<dim3(32, 32), 256, 0, stream>>>(Wo, WoT);
  gemm_out_half<<<dim3(16, 16, 2), 256, 0, stream>>>(ctxb, WoT, Po);
  reduce_out<<<2048, 256, 0, stream>>>(Po, (float*)d_out);
}

// Round 2
// 336.037 us; speedup vs baseline: 1.2826x; 1.2826x over previous
//
#include <hip/hip_runtime.h>

typedef unsigned short u16;
typedef float f32x4 __attribute__((ext_vector_type(4)));
typedef short s16x8 __attribute__((ext_vector_type(8)));
typedef short s16x4 __attribute__((ext_vector_type(4)));

__device__ __forceinline__ u16 f2b(float f) {
  union { float f; unsigned u; } v; v.f = f;
  unsigned r = v.u + 0x7fffu + ((v.u >> 16) & 1u);
  return (u16)(r >> 16);
}
__device__ __forceinline__ float b2f(u16 b) {
  union { unsigned u; float f; } v; v.u = ((unsigned)b) << 16;
  return v.f;
}
__device__ __forceinline__ f32x4 mfma_bf16(s16x8 a, s16x8 b, f32x4 c) {
  return __builtin_amdgcn_mfma_f32_16x16x32_bf16(a, b, c, 0, 0, 0);
}
__device__ __forceinline__ void gl_lds16(const u16* g, u16* l) {
  __builtin_amdgcn_global_load_lds(
      (const __attribute__((address_space(1))) void*)g,
      (__attribute__((address_space(3))) void*)l, 16, 0, 0);
}
// XOR-swizzled LDS index helpers (u16 units). byte ^= (row&7)<<4.
// kswz: stride-128-u16 tiles (Ks [64][128]); vswz: stride-64-u16 (Vs/Ps [128][64]).
__device__ __forceinline__ int kswz(int r, int c) { return ((r << 7) + c) ^ ((r & 7) << 3); }
__device__ __forceinline__ int vswz(int r, int c) { return ((r << 6) + c) ^ ((r & 7) << 3); }

// ---------------------------------------------------------------------------
// x fp32 -> bf16
// ---------------------------------------------------------------------------
__global__ void conv_x(const float* __restrict__ in, u16* __restrict__ out, int n) {
  int i = (blockIdx.x * 256 + threadIdx.x) * 8;
  if (i >= n) return;
  f32x4 a = *(const f32x4*)(in + i);
  f32x4 b = *(const f32x4*)(in + i + 4);
  s16x8 o = {(short)f2b(a.x), (short)f2b(a.y), (short)f2b(a.z), (short)f2b(a.w),
             (short)f2b(b.x), (short)f2b(b.y), (short)f2b(b.z), (short)f2b(b.w)};
  *(s16x8*)(out + i) = o;
}

// ---------------------------------------------------------------------------
// Weight transpose+convert fp32->bf16, 64x64 tiles.
// ---------------------------------------------------------------------------
__global__ void transW_qkv(const float* __restrict__ Wq, const float* __restrict__ Wk,
                           const float* __restrict__ Wv, u16* __restrict__ WqkvT) {
  __shared__ u16 tile[64][68];
  const int ox = blockIdx.x * 64;   // output-row base == source-col base
  const int oy = blockIdx.y * 64;   // source-row base
  const float* src; int scol, C;
  if (ox < 2048)      { src = Wq; scol = ox;        C = 2048; }
  else if (ox < 2560) { src = Wk; scol = ox - 2048; C = 512;  }
  else                { src = Wv; scol = ox - 2560; C = 512;  }
  const int t = threadIdx.x, lr = t >> 4, c4 = (t & 15) * 4;
#pragma unroll
  for (int p = 0; p < 4; ++p) {
    int r = p * 16 + lr;
    f32x4 v = *(const f32x4*)(src + (size_t)(oy + r) * C + scol + c4);
    s16x4 pk = {(short)f2b(v.x), (short)f2b(v.y), (short)f2b(v.z), (short)f2b(v.w)};
    *(s16x4*)(&tile[r][c4]) = pk;
  }
  __syncthreads();
#pragma unroll
  for (int q = 0; q < 4; ++q) {
    int oc = q * 16 + lr;
    s16x4 pk = {(short)tile[c4 + 0][oc], (short)tile[c4 + 1][oc],
                (short)tile[c4 + 2][oc], (short)tile[c4 + 3][oc]};
    *(s16x4*)(WqkvT + (size_t)(ox + oc) * 2048 + oy + c4) = pk;
  }
}

__global__ void transW_o(const float* __restrict__ Wo, u16* __restrict__ WoT) {
  __shared__ u16 tile[64][68];
  const int ox = blockIdx.x * 64, oy = blockIdx.y * 64;
  const int t = threadIdx.x, lr = t >> 4, c4 = (t & 15) * 4;
#pragma unroll
  for (int p = 0; p < 4; ++p) {
    int r = p * 16 + lr;
    f32x4 v = *(const f32x4*)(Wo + (size_t)(oy + r) * 2048 + ox + c4);
    s16x4 pk = {(short)f2b(v.x), (short)f2b(v.y), (short)f2b(v.z), (short)f2b(v.w)};
    *(s16x4*)(&tile[r][c4]) = pk;
  }
  __syncthreads();
#pragma unroll
  for (int q = 0; q < 4; ++q) {
    int oc = q * 16 + lr;
    s16x4 pk = {(short)tile[c4 + 0][oc], (short)tile[c4 + 1][oc],
                (short)tile[c4 + 2][oc], (short)tile[c4 + 3][oc]};
    *(s16x4*)(WoT + (size_t)(ox + oc) * 2048 + oy + c4) = pk;
  }
}

// v slice of qkv (cols 2560..3071) -> vT[512][2048]
__global__ void transpose_v(const u16* __restrict__ qkv, u16* __restrict__ vT) {
  __shared__ u16 tile[64][68];
  const int bx = blockIdx.x * 64, by = blockIdx.y * 64;
  const int t = threadIdx.x, lr = t >> 4, c4 = (t & 15) * 4;
#pragma unroll
  for (int p = 0; p < 4; ++p) {
    int r = p * 16 + lr;
    s16x4 v = *(const s16x4*)(qkv + (size_t)(by + r) * 3072 + 2560 + bx + c4);
    *(s16x4*)(&tile[r][c4]) = v;
  }
  __syncthreads();
#pragma unroll
  for (int q = 0; q < 4; ++q) {
    int oc = q * 16 + lr;
    s16x4 pk = {(short)tile[c4 + 0][oc], (short)tile[c4 + 1][oc],
                (short)tile[c4 + 2][oc], (short)tile[c4 + 3][oc]};
    *(s16x4*)(vT + (size_t)(bx + oc) * 2048 + by + c4) = pk;
  }
}

// ---------------------------------------------------------------------------
// 128x128 GEMM core (m97 structure), K-range parametrized for split-K.
// ---------------------------------------------------------------------------
__device__ __forceinline__ void gemm_core(const u16* __restrict__ A,
                                          const u16* __restrict__ Bt,
                                          int kbeg, int kend, int K,
                                          int m0, int n0,
                                          f32x4 (*acc)[4], u16* As, u16* Bs) {
  const int t = threadIdx.x;
  const int wave = t >> 6, lane = t & 63, quad = lane >> 4, lc = lane & 15;
  const int wm = (wave >> 1) * 64, wn = (wave & 1) * 64;
  for (int k0 = kbeg; k0 < kend; k0 += 32) {
#pragma unroll
    for (int h = 0; h < 2; ++h) {
      int ch = h * 256 + t, row = ch >> 2, kc = (ch & 3) * 8;
      gl_lds16(A  + (size_t)(m0 + row) * K + k0 + kc, As + (size_t)(h * 256 + wave * 64) * 8);
      gl_lds16(Bt + (size_t)(n0 + row) * K + k0 + kc, Bs + (size_t)(h * 256 + wave * 64) * 8);
    }
    __syncthreads();
    s16x8 af[4], bfr[4];
#pragma unroll
    for (int i = 0; i < 4; ++i)
      af[i] = *(const s16x8*)(As + (wm + i * 16 + lc) * 32 + quad * 8);
#pragma unroll
    for (int j = 0; j < 4; ++j)
      bfr[j] = *(const s16x8*)(Bs + (wn + j * 16 + lc) * 32 + quad * 8);
#pragma unroll
    for (int i = 0; i < 4; ++i)
#pragma unroll
      for (int j = 0; j < 4; ++j)
        acc[i][j] = mfma_bf16(af[i], bfr[j], acc[i][j]);
    __syncthreads();
  }
}

// QKV GEMM half: P[kh] = x @ WqkvT^T over K half.  grid (24,16,2).
__global__ __launch_bounds__(256, 2) void gemm_qkv_half(const u16* __restrict__ A,
                                                        const u16* __restrict__ Bt,
                                                        u16* __restrict__ P) {
  __shared__ __align__(16) u16 As[128 * 32];
  __shared__ __align__(16) u16 Bs[128 * 32];
  const int kh = blockIdx.z;
  const int n0 = blockIdx.x * 128, m0 = blockIdx.y * 128;
  const int lane = threadIdx.x & 63, wave = threadIdx.x >> 6;
  const int quad = lane >> 4, lc = lane & 15;
  const int wm = (wave >> 1) * 64, wn = (wave & 1) * 64;
  const f32x4 z = {0.f, 0.f, 0.f, 0.f};
  f32x4 acc[4][4];
#pragma unroll
  for (int i = 0; i < 4; ++i)
#pragma unroll
    for (int j = 0; j < 4; ++j) acc[i][j] = z;
  gemm_core(A, Bt, kh * 1024, kh * 1024 + 1024, 2048, m0, n0, acc, As, Bs);
  u16* Pk = P + (size_t)kh * (2048 * 3072);
#pragma unroll
  for (int i = 0; i < 4; ++i)
#pragma unroll
    for (int j = 0; j < 4; ++j)
#pragma unroll
      for (int r = 0; r < 4; ++r)
        Pk[(size_t)(m0 + wm + i * 16 + quad * 4 + r) * 3072 + n0 + wn + j * 16 + lc] =
            f2b(acc[i][j][r]);
}

// Reduce halves + RoPE (pairs are intra-vector) -> qkv bf16.  grid 3072.
__global__ void reduce_rope(const u16* __restrict__ P, u16* __restrict__ qkv) {
  const int lin = blockIdx.x * 256 + threadIdx.x;   // 0..786431
  const int row = lin / 384, c8 = (lin - row * 384) * 8;
  const u16* p0 = P + (size_t)row * 3072 + c8;
  s16x8 a = *(const s16x8*)p0;
  s16x8 b = *(const s16x8*)(p0 + 6291456);          // + 2048*3072
  float v[8];
#pragma unroll
  for (int i = 0; i < 8; ++i) v[i] = b2f((u16)a[i]) + b2f((u16)b[i]);
  if (c8 < 2560) {                                   // q|k cols get RoPE
#pragma unroll
    for (int h = 0; h < 4; ++h) {
      const int i = 2 * h;
      const int ip = ((c8 + i) & 127) >> 1;          // pair idx within head
      const float ang = (float)row * exp2f(-0.20762050593046014f * (float)ip);
      float sv, cv;
      sincosf(ang, &sv, &cv);
      const float e = v[i], o = v[i + 1];
      v[i]     = e * cv - o * sv;
      v[i + 1] = e * sv + o * cv;
    }
  }
  s16x8 o;
#pragma unroll
  for (int i = 0; i < 8; ++i) o[i] = (short)f2b(v[i]);
  *(s16x8*)(qkv + (size_t)row * 3072 + c8) = o;
}

// Out GEMM half: Po[kh] = ctx @ WoT^T over K half.  grid (16,16,2).
__global__ __launch_bounds__(256, 2) void gemm_out_half(const u16* __restrict__ A,
                                                        const u16* __restrict__ Bt,
                                                        u16* __restrict__ Po) {
  __shared__ __align__(16) u16 As[128 * 32];
  __shared__ __align__(16) u16 Bs[128 * 32];
  const int kh = blockIdx.z;
  const int n0 = blockIdx.x * 128, m0 = blockIdx.y * 128;
  const int lane = threadIdx.x & 63, wave = threadIdx.x >> 6;
  const int quad = lane >> 4, lc = lane & 15;
  const int wm = (wave >> 1) * 64, wn = (wave & 1) * 64;
  const f32x4 z = {0.f, 0.f, 0.f, 0.f};
  f32x4 acc[4][4];
#pragma unroll
  for (int i = 0; i < 4; ++i)
#pragma unroll
    for (int j = 0; j < 4; ++j) acc[i][j] = z;
  gemm_core(A, Bt, kh * 1024, kh * 1024 + 1024, 2048, m0, n0, acc, As, Bs);
  u16* Pk = Po + (size_t)kh * (2048 * 2048);
#pragma unroll
  for (int i = 0; i < 4; ++i)
#pragma unroll
    for (int j = 0; j < 4; ++j)
#pragma unroll
      for (int r = 0; r < 4; ++r)
        Pk[(size_t)(m0 + wm + i * 16 + quad * 4 + r) * 2048 + n0 + wn + j * 16 + lc] =
            f2b(acc[i][j][r]);
}

// Reduce out halves -> fp32 d_out.  grid 2048.
__global__ void reduce_out(const u16* __restrict__ Po, float* __restrict__ out) {
  const int lin = blockIdx.x * 256 + threadIdx.x;   // 0..524287
  const u16* p0 = Po + (size_t)lin * 8;
  s16x8 a = *(const s16x8*)p0;
  s16x8 b = *(const s16x8*)(p0 + 4194304);          // + 2048*2048
  f32x4 o0, o1;
#pragma unroll
  for (int i = 0; i < 4; ++i) o0[i] = b2f((u16)a[i]) + b2f((u16)b[i]);
#pragma unroll
  for (int i = 0; i < 4; ++i) o1[i] = b2f((u16)a[i + 4]) + b2f((u16)b[i + 4]);
  *(f32x4*)(out + (size_t)lin * 8) = o0;
  *(f32x4*)(out + (size_t)lin * 8 + 4) = o1;
}

// ---------------------------------------------------------------------------
// Attention v6: v5 structure (swizzled 48 KiB LDS, unmasked fast path,
// setprio, big-chunks-first) with launch_bounds reverted to (256,2).
// (256,3) made the allocator cap at 84 VGPR -> accumulator spills -> 746 MB
// scratch traffic. At (256,2) the kernel uses ~108 VGPR (no spill) and the
// 48 KiB LDS still yields 3 blocks/CU at runtime: min(160/48=3, 512/108=4).
// ---------------------------------------------------------------------------
__global__ __launch_bounds__(256, 2) void attn_k(const u16* __restrict__ qkv,
                                                 const u16* __restrict__ vT,
                                                 u16* __restrict__ Opart,
                                                 float* __restrict__ Lpart) {
  const int bid = blockIdx.x;
  const int hq = bid / 40, idx = 39 - (bid % 40);   // reversed: big chunks first
  int qt, c;
  if (idx < 4)       { qt = idx;                          c = 0; }
  else if (idx < 12) { int w = idx - 4;  qt = 4 + (w >> 1);  c = w & 1; }
  else if (idx < 24) { int w = idx - 12; qt = 8 + w / 3;     c = w % 3; }
  else               { int w = idx - 24; qt = 12 + (w >> 2); c = w & 3; }
  const int s0 = c * 8;
  const int s1 = min(c * 8 + 8, 2 * qt + 2);

  const int kvh = hq & 3;
  const int qc0 = hq << 7, kc0 = 2048 + (kvh << 7), vr0 = kvh << 7;

  // Unpadded, XOR-swizzled tiles: 3 x 16384 B = 48 KiB -> 3 blocks/CU.
  __shared__ __align__(16) u16 Ks[64 * 128];   // [j][d], kswz
  __shared__ __align__(16) u16 Vs[128 * 64];   // [d][j], vswz
  __shared__ __align__(16) u16 Ps[128 * 64];   // [q][j], vswz (per-wave private rows)

  const int t = threadIdx.x, wave = t >> 6, lane = t & 63;
  const int quad = lane >> 4, lc = lane & 15;
  const int kr = t >> 4, kc = (t & 15) * 8;
  const int vr = t >> 3, vc = (t & 7) * 8;

  s16x8 qf[2][4];
#pragma unroll
  for (int i = 0; i < 2; ++i)
#pragma unroll
    for (int ks = 0; ks < 4; ++ks)
      qf[i][ks] = *(const s16x8*)(qkv +
          (size_t)(qt * 128 + wave * 32 + i * 16 + lc) * 3072 +
          qc0 + ks * 32 + quad * 8);

  const f32x4 z = {0.f, 0.f, 0.f, 0.f};
  f32x4 oa[2][8];
#pragma unroll
  for (int i = 0; i < 2; ++i)
#pragma unroll
    for (int n = 0; n < 8; ++n) oa[i][n] = z;
  float Ls[2][4] = {{0.f, 0.f, 0.f, 0.f}, {0.f, 0.f, 0.f, 0.f}};
  const float scale2 = 0.12751744545f;

  s16x8 kpf[4], vpf[4];
  {
    const int j0 = s0 * 64;
#pragma unroll
    for (int p = 0; p < 4; ++p)
      kpf[p] = *(const s16x8*)(qkv + (size_t)(j0 + p * 16 + kr) * 3072 + kc0 + kc);
#pragma unroll
    for (int p = 0; p < 4; ++p)
      vpf[p] = *(const s16x8*)(vT + (size_t)(vr0 + p * 32 + vr) * 2048 + j0 + vc);
  }

  for (int tile = s0; tile < s1; ++tile) {
    const int j0 = tile * 64;
    __syncthreads();
#pragma unroll
    for (int p = 0; p < 4; ++p)
      *(s16x8*)(Ks + kswz(p * 16 + kr, kc)) = kpf[p];
#pragma unroll
    for (int p = 0; p < 4; ++p)
      *(s16x8*)(Vs + vswz(p * 32 + vr, vc)) = vpf[p];
    __syncthreads();
    if (tile + 1 < s1) {
      const int j1 = j0 + 64;
#pragma unroll
      for (int p = 0; p < 4; ++p)
        kpf[p] = *(const s16x8*)(qkv + (size_t)(j1 + p * 16 + kr) * 3072 + kc0 + kc);
#pragma unroll
      for (int p = 0; p < 4; ++p)
        vpf[p] = *(const s16x8*)(vT + (size_t)(vr0 + p * 32 + vr) * 2048 + j1 + vc);
    }
    f32x4 sa[2][4];
#pragma unroll
    for (int i = 0; i < 2; ++i)
#pragma unroll
      for (int n = 0; n < 4; ++n) sa[i][n] = z;
    __builtin_amdgcn_s_setprio(1);
#pragma unroll
    for (int ks = 0; ks < 4; ++ks)
#pragma unroll
      for (int n = 0; n < 4; ++n) {
        s16x8 bf = *(const s16x8*)(Ks + kswz(n * 16 + lc, ks * 32 + quad * 8));
        sa[0][n] = mfma_bf16(qf[0][ks], bf, sa[0][n]);
        sa[1][n] = mfma_bf16(qf[1][ks], bf, sa[1][n]);
      }
    __builtin_amdgcn_s_setprio(0);
    if (j0 + 64 <= qt * 128) {
      // Fully-unmasked tile (block-uniform): no causal compare needed.
#pragma unroll
      for (int i = 0; i < 2; ++i)
#pragma unroll
        for (int n = 0; n < 4; ++n)
#pragma unroll
          for (int r = 0; r < 4; ++r) {
            float e = exp2f(sa[i][n][r] * scale2);
            Ps[vswz(wave * 32 + i * 16 + quad * 4 + r, n * 16 + lc)] = f2b(e);
            Ls[i][r] += e;
          }
    } else {
#pragma unroll
      for (int i = 0; i < 2; ++i) {
        const int qrow_base = qt * 128 + wave * 32 + i * 16 + quad * 4;
#pragma unroll
        for (int n = 0; n < 4; ++n) {
          int jc = j0 + n * 16 + lc;
#pragma unroll
          for (int r = 0; r < 4; ++r) {
            float e = (jc <= qrow_base + r) ? exp2f(sa[i][n][r] * scale2) : 0.f;
            Ps[vswz(wave * 32 + i * 16 + quad * 4 + r, n * 16 + lc)] = f2b(e);
            Ls[i][r] += e;
          }
        }
      }
    }
    __builtin_amdgcn_s_setprio(1);
#pragma unroll
    for (int ks = 0; ks < 2; ++ks)
#pragma unroll
      for (int i = 0; i < 2; ++i) {
        s16x8 af = *(const s16x8*)(Ps + vswz(wave * 32 + i * 16 + lc,
                                             ks * 32 + quad * 8));
#pragma unroll
        for (int n = 0; n < 8; ++n) {
          s16x8 bf = *(const s16x8*)(Vs + vswz(n * 16 + lc, ks * 32 + quad * 8));
          oa[i][n] = mfma_bf16(af, bf, oa[i][n]);
        }
      }
    __builtin_amdgcn_s_setprio(0);
  }
#pragma unroll
  for (int i = 0; i < 2; ++i)
#pragma unroll
    for (int r = 0; r < 4; ++r) {
      float s = Ls[i][r];
      s += __shfl_xor(s, 1);
      s += __shfl_xor(s, 2);
      s += __shfl_xor(s, 4);
      s += __shfl_xor(s, 8);
      Ls[i][r] = s;
    }
  u16* Ob = Opart + (size_t)bid * (128 * 128);
  if (lc == 0) {
#pragma unroll
    for (int i = 0; i < 2; ++i)
#pragma unroll
      for (int r = 0; r < 4; ++r)
        Lpart[(size_t)bid * 128 + wave * 32 + i * 16 + quad * 4 + r] = Ls[i][r];
  }
#pragma unroll
  for (int i = 0; i < 2; ++i)
#pragma unroll
    for (int n = 0; n < 8; ++n)
#pragma unroll
      for (int r = 0; r < 4; ++r)
        Ob[(wave * 32 + i * 16 + quad * 4 + r) * 128 + n * 16 + lc] =
            f2b(oa[i][n][r]);
}

__global__ void attn_combine(const u16* __restrict__ Opart,
                             const float* __restrict__ Lpart,
                             u16* __restrict__ ctx) {
  const int hq = blockIdx.y, kvh = hq & 3, sg = hq >> 2;
  const int lin = blockIdx.x * 256 + threadIdx.x;
  const int token = lin >> 4, d8 = (lin & 15) << 3;
  const int qt = token >> 7, row = token & 127;
  const int tier = qt >> 2;
  const int btab[4] = {0, 4, 12, 24};
  const int base = btab[tier] + (qt & 3) * (tier + 1);
  const int cnt = tier + 1;
  float acc[8] = {0.f, 0.f, 0.f, 0.f, 0.f, 0.f, 0.f, 0.f};
  float L = 0.f;
  for (int c = 0; c < cnt; ++c) {
    const int b = hq * 40 + (39 - (base + c));   // matches reversed attn_k mapping
    L += Lpart[(size_t)b * 128 + row];
    s16x8 o = *(const s16x8*)(Opart + (size_t)b * 16384 + row * 128 + d8);
#pragma unroll
    for (int i = 0; i < 8; ++i) acc[i] += b2f((u16)o[i]);
  }
  const float inv = 1.f / L;
  s16x8 out;
#pragma unroll
  for (int i = 0; i < 8; ++i) out[i] = (short)f2b(acc[i] * inv);
  *(s16x8*)(ctx + (size_t)token * 2048 + ((kvh * 4 + sg) << 7) + d8) = out;
}

// ---------------------------------------------------------------------------
extern "C" void kernel_launch(void* const* d_in, const int* in_sizes, int n_in,
                              void* d_out, int out_size, void* d_ws, size_t ws_size,
                              hipStream_t stream) {
  const float* x  = (const float*)d_in[0];
  const float* Wq = (const float*)d_in[1];
  const float* Wk = (const float*)d_in[2];
  const float* Wv = (const float*)d_in[3];
  const float* Wo = (const float*)d_in[4];

  // Workspace choreography (peak ~50.3 MB; 52.4 MB proven available in R3):
  //  [0 .. 8.39M)    xb          -> later qkvb (12.58M) -> later WoT (8.39M)
  //  [8.39 .. 20.97) WqkvT       -> later vTb@12.58 (2.1M) + Lpart@14.68 (.33M)
  //  [20.97 .. 46.14) Pq0|Pq1    -> later Opart (20.97M) -> later Po0|Po1 (16.8M)
  //  [41.94 .. 50.33) ctxb (8.39M, starts exactly at Opart end)
  char* base = (char*)d_ws;
  u16*   xb    = (u16*)(base);
  u16*   qkvb  = (u16*)(base);                       // aliases xb+WqkvT head
  u16*   WoT   = (u16*)(base);                       // aliases qkvb (dead)
  u16*   WqkvT = (u16*)(base + 8388608);
  u16*   vTb   = (u16*)(base + 12582912);            // aliases WqkvT (dead)
  float* Lpart = (float*)(base + 14680064);
  u16*   Pq    = (u16*)(base + 20971520);            // 2 x 12.58M
  u16*   Opart = (u16*)(base + 20971520);            // aliases Pq (dead)
  u16*   Po    = (u16*)(base + 20971520);            // aliases Opart (dead)
  u16*   ctxb  = (u16*)(base + 41943040);

  // 1) convert x; transpose qkv weights
  conv_x<<<2048, 256, 0, stream>>>(x, xb, 2048 * 2048);
  transW_qkv<<<dim3(48, 32), 256, 0, stream>>>(Wq, Wk, Wv, WqkvT);

  // 2) split-K QKV projection -> bf16 partials -> reduce + RoPE
  gemm_qkv_half<<<dim3(24, 16, 2), 256, 0, stream>>>(xb, WqkvT, Pq);
  reduce_rope<<<3072, 256, 0, stream>>>(Pq, qkvb);

  // 3) v -> vT
  transpose_v<<<dim3(8, 32), 256, 0, stream>>>(qkvb, vTb);

  // 4) chunked attention + combine   [Opart overwrites Pq]
  attn_k<<<640, 256, 0, stream>>>(qkvb, vTb, Opart, Lpart);
  attn_combine<<<dim3(128, 16), 256, 0, stream>>>(Opart, Lpart, ctxb);

  // 5) transpose Wo (qkvb dead now), split-K out projection, reduce -> fp32
  transW_o<<<dim3(32, 32), 256, 0, stream>>>(Wo, WoT);
  gemm_out_half<<<dim3(16, 16, 2), 256, 0, stream>>>(ctxb, WoT, Po);
  reduce_out<<<2048, 256, 0, stream>>>(Po, (float*)d_out);
}

// Round 3
// 239.453 us; speedup vs baseline: 1.7999x; 1.4034x over previous
//
#include <hip/hip_runtime.h>

typedef unsigned short u16;
typedef float f32x4 __attribute__((ext_vector_type(4)));
typedef short s16x8 __attribute__((ext_vector_type(8)));
typedef short s16x4 __attribute__((ext_vector_type(4)));

__device__ __forceinline__ u16 f2b(float f) {
  union { float f; unsigned u; } v; v.f = f;
  unsigned r = v.u + 0x7fffu + ((v.u >> 16) & 1u);
  return (u16)(r >> 16);
}
__device__ __forceinline__ float b2f(u16 b) {
  union { unsigned u; float f; } v; v.u = ((unsigned)b) << 16;
  return v.f;
}
__device__ __forceinline__ f32x4 mfma_bf16(s16x8 a, s16x8 b, f32x4 c) {
  return __builtin_amdgcn_mfma_f32_16x16x32_bf16(a, b, c, 0, 0, 0);
}
__device__ __forceinline__ void gl_lds16(const u16* g, u16* l) {
  __builtin_amdgcn_global_load_lds(
      (const __attribute__((address_space(1))) void*)g,
      (__attribute__((address_space(3))) void*)l, 16, 0, 0);
}

// ---------------------------------------------------------------------------
// x fp32 -> bf16
// ---------------------------------------------------------------------------
__global__ void conv_x(const float* __restrict__ in, u16* __restrict__ out, int n) {
  int i = (blockIdx.x * 256 + threadIdx.x) * 8;
  if (i >= n) return;
  f32x4 a = *(const f32x4*)(in + i);
  f32x4 b = *(const f32x4*)(in + i + 4);
  s16x8 o = {(short)f2b(a.x), (short)f2b(a.y), (short)f2b(a.z), (short)f2b(a.w),
             (short)f2b(b.x), (short)f2b(b.y), (short)f2b(b.z), (short)f2b(b.w)};
  *(s16x8*)(out + i) = o;
}

// ---------------------------------------------------------------------------
// Weight transpose+convert fp32->bf16, 64x64 tiles.
// ---------------------------------------------------------------------------
__global__ void transW_qkv(const float* __restrict__ Wq, const float* __restrict__ Wk,
                           const float* __restrict__ Wv, u16* __restrict__ WqkvT) {
  __shared__ u16 tile[64][68];
  const int ox = blockIdx.x * 64;   // output-row base == source-col base
  const int oy = blockIdx.y * 64;   // source-row base
  const float* src; int scol, C;
  if (ox < 2048)      { src = Wq; scol = ox;        C = 2048; }
  else if (ox < 2560) { src = Wk; scol = ox - 2048; C = 512;  }
  else                { src = Wv; scol = ox - 2560; C = 512;  }
  const int t = threadIdx.x, lr = t >> 4, c4 = (t & 15) * 4;
#pragma unroll
  for (int p = 0; p < 4; ++p) {
    int r = p * 16 + lr;
    f32x4 v = *(const f32x4*)(src + (size_t)(oy + r) * C + scol + c4);
    s16x4 pk = {(short)f2b(v.x), (short)f2b(v.y), (short)f2b(v.z), (short)f2b(v.w)};
    *(s16x4*)(&tile[r][c4]) = pk;
  }
  __syncthreads();
#pragma unroll
  for (int q = 0; q < 4; ++q) {
    int oc = q * 16 + lr;
    s16x4 pk = {(short)tile[c4 + 0][oc], (short)tile[c4 + 1][oc],
                (short)tile[c4 + 2][oc], (short)tile[c4 + 3][oc]};
    *(s16x4*)(WqkvT + (size_t)(ox + oc) * 2048 + oy + c4) = pk;
  }
}

__global__ void transW_o(const float* __restrict__ Wo, u16* __restrict__ WoT) {
  __shared__ u16 tile[64][68];
  const int ox = blockIdx.x * 64, oy = blockIdx.y * 64;
  const int t = threadIdx.x, lr = t >> 4, c4 = (t & 15) * 4;
#pragma unroll
  for (int p = 0; p < 4; ++p) {
    int r = p * 16 + lr;
    f32x4 v = *(const f32x4*)(Wo + (size_t)(oy + r) * 2048 + ox + c4);
    s16x4 pk = {(short)f2b(v.x), (short)f2b(v.y), (short)f2b(v.z), (short)f2b(v.w)};
    *(s16x4*)(&tile[r][c4]) = pk;
  }
  __syncthreads();
#pragma unroll
  for (int q = 0; q < 4; ++q) {
    int oc = q * 16 + lr;
    s16x4 pk = {(short)tile[c4 + 0][oc], (short)tile[c4 + 1][oc],
                (short)tile[c4 + 2][oc], (short)tile[c4 + 3][oc]};
    *(s16x4*)(WoT + (size_t)(ox + oc) * 2048 + oy + c4) = pk;
  }
}

// v slice of qkv (cols 2560..3071) -> vT[512][2048]
__global__ void transpose_v(const u16* __restrict__ qkv, u16* __restrict__ vT) {
  __shared__ u16 tile[64][68];
  const int bx = blockIdx.x * 64, by = blockIdx.y * 64;
  const int t = threadIdx.x, lr = t >> 4, c4 = (t & 15) * 4;
#pragma unroll
  for (int p = 0; p < 4; ++p) {
    int r = p * 16 + lr;
    s16x4 v = *(const s16x4*)(qkv + (size_t)(by + r) * 3072 + 2560 + bx + c4);
    *(s16x4*)(&tile[r][c4]) = v;
  }
  __syncthreads();
#pragma unroll
  for (int q = 0; q < 4; ++q) {
    int oc = q * 16 + lr;
    s16x4 pk = {(short)tile[c4 + 0][oc], (short)tile[c4 + 1][oc],
                (short)tile[c4 + 2][oc], (short)tile[c4 + 3][oc]};
    *(s16x4*)(vT + (size_t)(bx + oc) * 2048 + by + c4) = pk;
  }
}

// ---------------------------------------------------------------------------
// 128x128 GEMM core (m97 structure), K-range parametrized for split-K.
// ---------------------------------------------------------------------------
__device__ __forceinline__ void gemm_core(const u16* __restrict__ A,
                                          const u16* __restrict__ Bt,
                                          int kbeg, int kend, int K,
                                          int m0, int n0,
                                          f32x4 (*acc)[4], u16* As, u16* Bs) {
  const int t = threadIdx.x;
  const int wave = t >> 6, lane = t & 63, quad = lane >> 4, lc = lane & 15;
  const int wm = (wave >> 1) * 64, wn = (wave & 1) * 64;
  for (int k0 = kbeg; k0 < kend; k0 += 32) {
#pragma unroll
    for (int h = 0; h < 2; ++h) {
      int ch = h * 256 + t, row = ch >> 2, kc = (ch & 3) * 8;
      gl_lds16(A  + (size_t)(m0 + row) * K + k0 + kc, As + (size_t)(h * 256 + wave * 64) * 8);
      gl_lds16(Bt + (size_t)(n0 + row) * K + k0 + kc, Bs + (size_t)(h * 256 + wave * 64) * 8);
    }
    __syncthreads();
    s16x8 af[4], bfr[4];
#pragma unroll
    for (int i = 0; i < 4; ++i)
      af[i] = *(const s16x8*)(As + (wm + i * 16 + lc) * 32 + quad * 8);
#pragma unroll
    for (int j = 0; j < 4; ++j)
      bfr[j] = *(const s16x8*)(Bs + (wn + j * 16 + lc) * 32 + quad * 8);
#pragma unroll
    for (int i = 0; i < 4; ++i)
#pragma unroll
      for (int j = 0; j < 4; ++j)
        acc[i][j] = mfma_bf16(af[i], bfr[j], acc[i][j]);
    __syncthreads();
  }
}

// QKV GEMM half: P[kh] = x @ WqkvT^T over K half.  grid (24,16,2).
__global__ __launch_bounds__(256, 2) void gemm_qkv_half(const u16* __restrict__ A,
                                                        const u16* __restrict__ Bt,
                                                        u16* __restrict__ P) {
  __shared__ __align__(16) u16 As[128 * 32];
  __shared__ __align__(16) u16 Bs[128 * 32];
  const int kh = blockIdx.z;
  const int n0 = blockIdx.x * 128, m0 = blockIdx.y * 128;
  const int lane = threadIdx.x & 63, wave = threadIdx.x >> 6;
  const int quad = lane >> 4, lc = lane & 15;
  const int wm = (wave >> 1) * 64, wn = (wave & 1) * 64;
  const f32x4 z = {0.f, 0.f, 0.f, 0.f};
  f32x4 acc[4][4];
#pragma unroll
  for (int i = 0; i < 4; ++i)
#pragma unroll
    for (int j = 0; j < 4; ++j) acc[i][j] = z;
  gemm_core(A, Bt, kh * 1024, kh * 1024 + 1024, 2048, m0, n0, acc, As, Bs);
  u16* Pk = P + (size_t)kh * (2048 * 3072);
#pragma unroll
  for (int i = 0; i < 4; ++i)
#pragma unroll
    for (int j = 0; j < 4; ++j)
#pragma unroll
      for (int r = 0; r < 4; ++r)
        Pk[(size_t)(m0 + wm + i * 16 + quad * 4 + r) * 3072 + n0 + wn + j * 16 + lc] =
            f2b(acc[i][j][r]);
}

// Reduce halves + RoPE (pairs are intra-vector) -> qkv bf16.  grid 3072.
__global__ void reduce_rope(const u16* __restrict__ P, u16* __restrict__ qkv) {
  const int lin = blockIdx.x * 256 + threadIdx.x;   // 0..786431
  const int row = lin / 384, c8 = (lin - row * 384) * 8;
  const u16* p0 = P + (size_t)row * 3072 + c8;
  s16x8 a = *(const s16x8*)p0;
  s16x8 b = *(const s16x8*)(p0 + 6291456);          // + 2048*3072
  float v[8];
#pragma unroll
  for (int i = 0; i < 8; ++i) v[i] = b2f((u16)a[i]) + b2f((u16)b[i]);
  if (c8 < 2560) {                                   // q|k cols get RoPE
#pragma unroll
    for (int h = 0; h < 4; ++h) {
      const int i = 2 * h;
      const int ip = ((c8 + i) & 127) >> 1;          // pair idx within head
      const float ang = (float)row * exp2f(-0.20762050593046014f * (float)ip);
      float sv, cv;
      sincosf(ang, &sv, &cv);
      const float e = v[i], o = v[i + 1];
      v[i]     = e * cv - o * sv;
      v[i + 1] = e * sv + o * cv;
    }
  }
  s16x8 o;
#pragma unroll
  for (int i = 0; i < 8; ++i) o[i] = (short)f2b(v[i]);
  *(s16x8*)(qkv + (size_t)row * 3072 + c8) = o;
}

// Out GEMM half: Po[kh] = ctx @ WoT^T over K half.  grid (16,16,2).
__global__ __launch_bounds__(256, 2) void gemm_out_half(const u16* __restrict__ A,
                                                        const u16* __restrict__ Bt,
                                                        u16* __restrict__ Po) {
  __shared__ __align__(16) u16 As[128 * 32];
  __shared__ __align__(16) u16 Bs[128 * 32];
  const int kh = blockIdx.z;
  const int n0 = blockIdx.x * 128, m0 = blockIdx.y * 128;
  const int lane = threadIdx.x & 63, wave = threadIdx.x >> 6;
  const int quad = lane >> 4, lc = lane & 15;
  const int wm = (wave >> 1) * 64, wn = (wave & 1) * 64;
  const f32x4 z = {0.f, 0.f, 0.f, 0.f};
  f32x4 acc[4][4];
#pragma unroll
  for (int i = 0; i < 4; ++i)
#pragma unroll
    for (int j = 0; j < 4; ++j) acc[i][j] = z;
  gemm_core(A, Bt, kh * 1024, kh * 1024 + 1024, 2048, m0, n0, acc, As, Bs);
  u16* Pk = Po + (size_t)kh * (2048 * 2048);
#pragma unroll
  for (int i = 0; i < 4; ++i)
#pragma unroll
    for (int j = 0; j < 4; ++j)
#pragma unroll
      for (int r = 0; r < 4; ++r)
        Pk[(size_t)(m0 + wm + i * 16 + quad * 4 + r) * 2048 + n0 + wn + j * 16 + lc] =
            f2b(acc[i][j][r]);
}

// Reduce out halves -> fp32 d_out.  grid 2048.
__global__ void reduce_out(const u16* __restrict__ Po, float* __restrict__ out) {
  const int lin = blockIdx.x * 256 + threadIdx.x;   // 0..524287
  const u16* p0 = Po + (size_t)lin * 8;
  s16x8 a = *(const s16x8*)p0;
  s16x8 b = *(const s16x8*)(p0 + 4194304);          // + 2048*2048
  f32x4 o0, o1;
#pragma unroll
  for (int i = 0; i < 4; ++i) o0[i] = b2f((u16)a[i]) + b2f((u16)b[i]);
#pragma unroll
  for (int i = 0; i < 4; ++i) o1[i] = b2f((u16)a[i + 4]) + b2f((u16)b[i + 4]);
  *(f32x4*)(out + (size_t)lin * 8) = o0;
  *(f32x4*)(out + (size_t)lin * 8 + 4) = o1;
}

// ---------------------------------------------------------------------------
// Attention v4-baseline + setprio (T5) only. The v5/v6 rewrite (swizzle +
// dual-path epilogue) raised register demand past the allocator's budget and
// spilled the accumulators inside the tile loop (WRITE_SIZE 176-403 MB vs
// 21 MB real output). Baseline: 108 VGPR, zero spill, 59.3 us proven.
// setprio is scheduling-only (SALU hint), cannot perturb regalloc.
// ---------------------------------------------------------------------------
__global__ __launch_bounds__(256, 2) void attn_k(const u16* __restrict__ qkv,
                                                 const u16* __restrict__ vT,
                                                 u16* __restrict__ Opart,
                                                 float* __restrict__ Lpart) {
  const int bid = blockIdx.x;
  const int hq = bid / 40, idx = bid % 40;
  int qt, c;
  if (idx < 4)       { qt = idx;                          c = 0; }
  else if (idx < 12) { int w = idx - 4;  qt = 4 + (w >> 1);  c = w & 1; }
  else if (idx < 24) { int w = idx - 12; qt = 8 + w / 3;     c = w % 3; }
  else               { int w = idx - 24; qt = 12 + (w >> 2); c = w & 3; }
  const int s0 = c * 8;
  const int s1 = min(c * 8 + 8, 2 * qt + 2);

  const int kvh = hq & 3;
  const int qc0 = hq << 7, kc0 = 2048 + (kvh << 7), vr0 = kvh << 7;

  __shared__ __align__(16) u16 Ks[64 * 136];
  __shared__ __align__(16) u16 Vs[128 * 72];
  __shared__ __align__(16) u16 Ps[128 * 72];

  const int t = threadIdx.x, wave = t >> 6, lane = t & 63;
  const int quad = lane >> 4, lc = lane & 15;
  const int kr = t >> 4, kc = (t & 15) * 8;
  const int vr = t >> 3, vc = (t & 7) * 8;

  s16x8 qf[2][4];
#pragma unroll
  for (int i = 0; i < 2; ++i)
#pragma unroll
    for (int ks = 0; ks < 4; ++ks)
      qf[i][ks] = *(const s16x8*)(qkv +
          (size_t)(qt * 128 + wave * 32 + i * 16 + lc) * 3072 +
          qc0 + ks * 32 + quad * 8);

  const f32x4 z = {0.f, 0.f, 0.f, 0.f};
  f32x4 oa[2][8];
#pragma unroll
  for (int i = 0; i < 2; ++i)
#pragma unroll
    for (int n = 0; n < 8; ++n) oa[i][n] = z;
  float Ls[2][4] = {{0.f, 0.f, 0.f, 0.f}, {0.f, 0.f, 0.f, 0.f}};
  const float scale2 = 0.12751744545f;

  s16x8 kpf[4], vpf[4];
  {
    const int j0 = s0 * 64;
#pragma unroll
    for (int p = 0; p < 4; ++p)
      kpf[p] = *(const s16x8*)(qkv + (size_t)(j0 + p * 16 + kr) * 3072 + kc0 + kc);
#pragma unroll
    for (int p = 0; p < 4; ++p)
      vpf[p] = *(const s16x8*)(vT + (size_t)(vr0 + p * 32 + vr) * 2048 + j0 + vc);
  }

  for (int tile = s0; tile < s1; ++tile) {
    const int j0 = tile * 64;
    __syncthreads();
#pragma unroll
    for (int p = 0; p < 4; ++p)
      *(s16x8*)(Ks + (p * 16 + kr) * 136 + kc) = kpf[p];
#pragma unroll
    for (int p = 0; p < 4; ++p)
      *(s16x8*)(Vs + (p * 32 + vr) * 72 + vc) = vpf[p];
    __syncthreads();
    if (tile + 1 < s1) {
      const int j1 = j0 + 64;
#pragma unroll
      for (int p = 0; p < 4; ++p)
        kpf[p] = *(const s16x8*)(qkv + (size_t)(j1 + p * 16 + kr) * 3072 + kc0 + kc);
#pragma unroll
      for (int p = 0; p < 4; ++p)
        vpf[p] = *(const s16x8*)(vT + (size_t)(vr0 + p * 32 + vr) * 2048 + j1 + vc);
    }
    f32x4 sa[2][4];
#pragma unroll
    for (int i = 0; i < 2; ++i)
#pragma unroll
      for (int n = 0; n < 4; ++n) sa[i][n] = z;
    __builtin_amdgcn_s_setprio(1);
#pragma unroll
    for (int ks = 0; ks < 4; ++ks)
#pragma unroll
      for (int n = 0; n < 4; ++n) {
        s16x8 bf = *(const s16x8*)(Ks + (n * 16 + lc) * 136 + ks * 32 + quad * 8);
        sa[0][n] = mfma_bf16(qf[0][ks], bf, sa[0][n]);
        sa[1][n] = mfma_bf16(qf[1][ks], bf, sa[1][n]);
      }
    __builtin_amdgcn_s_setprio(0);
#pragma unroll
    for (int i = 0; i < 2; ++i) {
      const int qrow_base = qt * 128 + wave * 32 + i * 16 + quad * 4;
#pragma unroll
      for (int n = 0; n < 4; ++n) {
        int jc = j0 + n * 16 + lc;
#pragma unroll
        for (int r = 0; r < 4; ++r) {
          float e = (jc <= qrow_base + r) ? exp2f(sa[i][n][r] * scale2) : 0.f;
          Ps[(wave * 32 + i * 16 + quad * 4 + r) * 72 + n * 16 + lc] = f2b(e);
          Ls[i][r] += e;
        }
      }
    }
    __builtin_amdgcn_s_setprio(1);
#pragma unroll
    for (int ks = 0; ks < 2; ++ks)
#pragma unroll
      for (int i = 0; i < 2; ++i) {
        s16x8 af = *(const s16x8*)(Ps + (wave * 32 + i * 16 + lc) * 72 +
                                   ks * 32 + quad * 8);
#pragma unroll
        for (int n = 0; n < 8; ++n) {
          s16x8 bf = *(const s16x8*)(Vs + (n * 16 + lc) * 72 + ks * 32 + quad * 8);
          oa[i][n] = mfma_bf16(af, bf, oa[i][n]);
        }
      }
    __builtin_amdgcn_s_setprio(0);
  }
#pragma unroll
  for (int i = 0; i < 2; ++i)
#pragma unroll
    for (int r = 0; r < 4; ++r) {
      float s = Ls[i][r];
      s += __shfl_xor(s, 1);
      s += __shfl_xor(s, 2);
      s += __shfl_xor(s, 4);
      s += __shfl_xor(s, 8);
      Ls[i][r] = s;
    }
  u16* Ob = Opart + (size_t)bid * (128 * 128);
  if (lc == 0) {
#pragma unroll
    for (int i = 0; i < 2; ++i)
#pragma unroll
      for (int r = 0; r < 4; ++r)
        Lpart[(size_t)bid * 128 + wave * 32 + i * 16 + quad * 4 + r] = Ls[i][r];
  }
#pragma unroll
  for (int i = 0; i < 2; ++i)
#pragma unroll
    for (int n = 0; n < 8; ++n)
#pragma unroll
      for (int r = 0; r < 4; ++r)
        Ob[(wave * 32 + i * 16 + quad * 4 + r) * 128 + n * 16 + lc] =
            f2b(oa[i][n][r]);
}

__global__ void attn_combine(const u16* __restrict__ Opart,
                             const float* __restrict__ Lpart,
                             u16* __restrict__ ctx) {
  const int hq = blockIdx.y, kvh = hq & 3, sg = hq >> 2;
  const int lin = blockIdx.x * 256 + threadIdx.x;
  const int token = lin >> 4, d8 = (lin & 15) << 3;
  const int qt = token >> 7, row = token & 127;
  const int tier = qt >> 2;
  const int btab[4] = {0, 4, 12, 24};
  const int base = hq * 40 + btab[tier] + (qt & 3) * (tier + 1);
  const int cnt = tier + 1;
  float acc[8] = {0.f, 0.f, 0.f, 0.f, 0.f, 0.f, 0.f, 0.f};
  float L = 0.f;
  for (int c = 0; c < cnt; ++c) {
    const int b = base + c;
    L += Lpart[(size_t)b * 128 + row];
    s16x8 o = *(const s16x8*)(Opart + (size_t)b * 16384 + row * 128 + d8);
#pragma unroll
    for (int i = 0; i < 8; ++i) acc[i] += b2f((u16)o[i]);
  }
  const float inv = 1.f / L;
  s16x8 out;
#pragma unroll
  for (int i = 0; i < 8; ++i) out[i] = (short)f2b(acc[i] * inv);
  *(s16x8*)(ctx + (size_t)token * 2048 + ((kvh * 4 + sg) << 7) + d8) = out;
}

// ---------------------------------------------------------------------------
extern "C" void kernel_launch(void* const* d_in, const int* in_sizes, int n_in,
                              void* d_out, int out_size, void* d_ws, size_t ws_size,
                              hipStream_t stream) {
  const float* x  = (const float*)d_in[0];
  const float* Wq = (const float*)d_in[1];
  const float* Wk = (const float*)d_in[2];
  const float* Wv = (const float*)d_in[3];
  const float* Wo = (const float*)d_in[4];

  // Workspace choreography (peak ~50.3 MB; 52.4 MB proven available in R3):
  //  [0 .. 8.39M)    xb          -> later qkvb (12.58M) -> later WoT (8.39M)
  //  [8.39 .. 20.97) WqkvT       -> later vTb@12.58 (2.1M) + Lpart@14.68 (.33M)
  //  [20.97 .. 46.14) Pq0|Pq1    -> later Opart (20.97M) -> later Po0|Po1 (16.8M)
  //  [41.94 .. 50.33) ctxb (8.39M, starts exactly at Opart end)
  char* base = (char*)d_ws;
  u16*   xb    = (u16*)(base);
  u16*   qkvb  = (u16*)(base);                       // aliases xb+WqkvT head
  u16*   WoT   = (u16*)(base);                       // aliases qkvb (dead)
  u16*   WqkvT = (u16*)(base + 8388608);
  u16*   vTb   = (u16*)(base + 12582912);            // aliases WqkvT (dead)
  float* Lpart = (float*)(base + 14680064);
  u16*   Pq    = (u16*)(base + 20971520);            // 2 x 12.58M
  u16*   Opart = (u16*)(base + 20971520);            // aliases Pq (dead)
  u16*   Po    = (u16*)(base + 20971520);            // aliases Opart (dead)
  u16*   ctxb  = (u16*)(base + 41943040);

  // 1) convert x; transpose qkv weights
  conv_x<<<2048, 256, 0, stream>>>(x, xb, 2048 * 2048);
  transW_qkv<<<dim3(48, 32), 256, 0, stream>>>(Wq, Wk, Wv, WqkvT);

  // 2) split-K QKV projection -> bf16 partials -> reduce + RoPE
  gemm_qkv_half<<<dim3(24, 16, 2), 256, 0, stream>>>(xb, WqkvT, Pq);
  reduce_rope<<<3072, 256, 0, stream>>>(Pq, qkvb);

  // 3) v -> vT
  transpose_v<<<dim3(8, 32), 256, 0, stream>>>(qkvb, vTb);

  // 4) chunked attention + combine   [Opart overwrites Pq]
  attn_k<<<640, 256, 0, stream>>>(qkvb, vTb, Opart, Lpart);
  attn_combine<<<dim3(128, 16), 256, 0, stream>>>(Opart, Lpart, ctxb);

  // 5) transpose Wo (qkvb dead now), split-K out projection, reduce -> fp32
  transW_o<<<dim3(32, 32), 256, 0, stream>>>(Wo, WoT);
  gemm_out_half<<<dim3(16, 16, 2), 256, 0, stream>>>(ctxb, WoT, Po);
  reduce_out<<<2048, 256, 0, stream>>>(Po, (float*)d_out);
}